// Round 21
// baseline (172.941 us; speedup 1.0000x reference)
//
#include <hip/hip_runtime.h>
#include <cstdint>
#include <cstddef>

// VmfVectorQuantizer round 21: LDS codebook (R17) + 4 waves per 16-row tile
// (128 codes/wave) in 1024-thread blocks -> 4 waves/SIMD with a ~115-reg
// live set that fits the 128-reg/thread hard cap WITHOUT spill. 4-way acc2
// merge via LDS ds_add_f32 atomics (one barrier).

typedef __attribute__((ext_vector_type(8))) short short8;
typedef __attribute__((ext_vector_type(4))) float f32x4;

namespace {
constexpr float kEpsG = 1e-10f;
constexpr float kEpsN = 1e-12f;
constexpr float kEpsP = 1e-7f;
constexpr float kLog2e = 1.4426950408889634f;
constexpr float kLn2 = 0.6931471805599453f;
constexpr int kSlots = 128;
constexpr int kStride = 520;
// dynamic LDS layout (bytes)
constexpr int kOffCbt = 65536;    // [64][512] bf16 swizzled   65536
constexpr int kOffAvg = 131072;   // float [512]                2048
constexpr int kOffCS  = 133120;   // float [4][4][16] x3        3072
constexpr int kOffAcz = 136192;   // float [4][4][64][4]       16384
constexpr int kLdsBytes = 152576;
}

__device__ __forceinline__ float wsum64(float v) {
#pragma unroll
    for (int m = 1; m < 64; m <<= 1) v += __shfl_xor(v, m, 64);
    return v;
}
__device__ __forceinline__ uint32_t pk_bf16(float a, float b) {
    uint32_t ua = __float_as_uint(a), ub = __float_as_uint(b);
    ua += 0x7fffu + ((ua >> 16) & 1u);
    ub += 0x7fffu + ((ub >> 16) & 1u);
    return (ua >> 16) | (ub & 0xffff0000u);
}
__device__ __forceinline__ uint16_t bf16_rne(float a) {
    uint32_t ua = __float_as_uint(a);
    ua += 0x7fffu + ((ua >> 16) & 1u);
    return (uint16_t)(ua >> 16);
}
__device__ __forceinline__ float dot4(float4 v) {
    return v.x * v.x + v.y * v.y + v.z * v.z + v.w * v.w;
}

__global__ __launch_bounds__(256) void k_prep(const float* __restrict__ cb,
                                              uint16_t* __restrict__ cbN,
                                              uint16_t* __restrict__ cbNT) {
    const int row = blockIdx.x * 4 + (threadIdx.x >> 6);
    const int lane = threadIdx.x & 63;
    const float v = cb[row * 64 + lane];
    const float ss = wsum64(v * v);
    const float nv = v / fmaxf(sqrtf(ss), kEpsN);
    const uint16_t h = bf16_rne(nv);
    cbN[row * 64 + lane] = h;
    cbNT[lane * 512 + row] = h;
}

// ---- k_main: 1024 blocks x 1024 threads (16 waves = 4 tiles x 4 waves).
// Tile tp covers rows [blk*64 + 16tp, +16); wave W owns codes [128W,+128).
__global__ __launch_bounds__(1024) void k_main(
    const float* __restrict__ z, const float* __restrict__ kqp,
    const float* __restrict__ gum, const uint16_t* __restrict__ cbN,
    const uint16_t* __restrict__ cbNT, float* __restrict__ out,
    float* __restrict__ g_part) {
    extern __shared__ float4 smem_al[];
    char* smem = (char*)smem_al;
    float* avg1 = (float*)(smem + kOffAvg);
    float (*cS)[4][16]  = (float(*)[4][16])(smem + kOffCS);
    float (*cW)[4][16]  = (float(*)[4][16])(smem + kOffCS + 1024);
    float (*cS2)[4][16] = (float(*)[4][16])(smem + kOffCS + 2048);
    float* accZ = (float*)(smem + kOffAcz);  // [tp][dt][lane][4]

    const int tid = threadIdx.x;
    const int wv = tid >> 6;   // 0..15
    const int tp = wv >> 2;    // tile 0..3
    const int W = wv & 3;      // code quarter
    const int l = tid & 63;
    const int g = l >> 4;
    const int rh = l & 15;
    const int r0 = blockIdx.x * 64 + tp * 16;
    const int row = r0 + rh;
    const float kq = *kqp;

    // ---- init avg + accZ, stage codebook into swizzled LDS ----
    if (tid < 512) avg1[tid] = 0.f;
#pragma unroll
    for (int j = 0; j < 4; ++j) accZ[tid + 1024 * j] = 0.f;
#pragma unroll
    for (int it = 0; it < 8; ++it) {
        const int i = tid + 1024 * it;          // 8192 chunks
        const uint4 v = ((const uint4*)cbN)[i];
        const int r = i >> 3, c = i & 7;
        *(uint4*)(smem + r * 128 + ((c ^ (r & 7)) << 4)) = v;
    }
#pragma unroll
    for (int it = 0; it < 4; ++it) {
        const int i = tid + 1024 * it;          // 4096 chunks
        const uint4 v = ((const uint4*)cbNT)[i];
        const int d = i >> 6, c = i & 63;
        *(uint4*)(smem + kOffCbt + d * 1024 + ((c ^ (d & 7)) << 4)) = v;
    }

    // ---- z load + L2 normalize; fold kq*log2e into bf16 B-fragments
    const float* zr = z + (size_t)row * 64;
    const float4 a0 = *(const float4*)(zr + 8 * g);
    const float4 a1 = *(const float4*)(zr + 8 * g + 4);
    const float4 a2 = *(const float4*)(zr + 32 + 8 * g);
    const float4 a3 = *(const float4*)(zr + 36 + 8 * g);
    float ss = dot4(a0) + dot4(a1) + dot4(a2) + dot4(a3);
    ss += __shfl_xor(ss, 16, 64);
    ss += __shfl_xor(ss, 32, 64);
    const float scz = kq * kLog2e / fmaxf(sqrtf(ss), kEpsN);
    union U8 { short8 s; uint32_t u[4]; };
    U8 zb0, zb1;
    zb0.u[0] = pk_bf16(a0.x * scz, a0.y * scz);
    zb0.u[1] = pk_bf16(a0.z * scz, a0.w * scz);
    zb0.u[2] = pk_bf16(a1.x * scz, a1.y * scz);
    zb0.u[3] = pk_bf16(a1.z * scz, a1.w * scz);
    zb1.u[0] = pk_bf16(a2.x * scz, a2.y * scz);
    zb1.u[1] = pk_bf16(a2.z * scz, a2.w * scz);
    zb1.u[2] = pk_bf16(a3.x * scz, a3.y * scz);
    zb1.u[3] = pk_bf16(a3.z * scz, a3.w * scz);

    const float B1 = kq * kLog2e;  // static bound: x <= B1

    // ---- u tiles 0,1 prefetched (stream under staging + barrier)
    const float* ur = gum + (size_t)row * 512 + 128 * W;
    float4 u0[4], u1[4];
#pragma unroll
    for (int j = 0; j < 4; ++j) u0[j] = *(const float4*)(ur + 16 * j + 4 * g);
#pragma unroll
    for (int j = 0; j < 4; ++j)
        u1[j] = *(const float4*)(ur + 64 + 16 * j + 4 * g);

    __syncthreads();  // codebook + avg/accZ init ready

    // ============== fused loop: GEMM1 -> e -> gumbel -> GEMM2 =============
    uint32_t epk[16];
    float S4[4] = {0.f, 0.f, 0.f, 0.f}, W4[4] = {0.f, 0.f, 0.f, 0.f};
    float S24[4] = {0.f, 0.f, 0.f, 0.f};
    f32x4 acc2[4];
#pragma unroll
    for (int dt = 0; dt < 4; ++dt) acc2[dt] = (f32x4){0.f, 0.f, 0.f, 0.f};
    const int srcA = rh + 16 * ((2 * g) & 3);
    const int srcB = rh + 16 * ((2 * g + 1) & 3);
    const bool hi = (g & 2) != 0;

#pragma unroll
    for (int T = 0; T < 2; ++T) {
        float pf[8];
#pragma unroll
        for (int q = 0; q < 4; ++q) {
            const int R = 128 * W + 64 * T + 16 * q + rh;
            const char* rb = smem + R * 128;
            const short8 ca0 = *(const short8*)(rb + ((g ^ (R & 7)) << 4));
            const short8 ca1 = *(const short8*)(rb + (((g + 4) ^ (R & 7)) << 4));
            f32x4 acc = {0.f, 0.f, 0.f, 0.f};
            acc = __builtin_amdgcn_mfma_f32_16x16x32_bf16(ca0, zb0.s, acc, 0, 0, 0);
            acc = __builtin_amdgcn_mfma_f32_16x16x32_bf16(ca1, zb1.s, acc, 0, 0, 0);
            const float4 uq = (T == 0) ? u0[q] : u1[q];
            const float uu[4] = {uq.x, uq.y, uq.z, uq.w};
            float e4[4], e2v[4];
#pragma unroll
            for (int i = 0; i < 4; ++i) {
                const float d = acc[i] - B1;
                const float e = __builtin_amdgcn_exp2f(d);
                e4[i] = e;
                S4[i] += e;
                W4[i] = fmaf(d, e, W4[i]);
                const float lg = __builtin_amdgcn_logf(uu[i] + kEpsG);
                const float inr = fmaf(lg, -kLn2, kEpsG);
                const float r = __builtin_amdgcn_rcpf(inr);
                const float t = e * r;
                const float e2 = t * t;
                e2v[i] = e2;
                S24[i] += e2;
            }
            epk[8 * T + 2 * q] = pk_bf16(e4[0], e4[1]);
            epk[8 * T + 2 * q + 1] = pk_bf16(e4[2], e4[3]);
            pf[2 * q] = __uint_as_float(pk_bf16(e2v[0], e2v[1]));
            pf[2 * q + 1] = __uint_as_float(pk_bf16(e2v[2], e2v[3]));
        }
#pragma unroll
        for (int ks = 0; ks < 2; ++ks) {
            const float a0lo = __shfl(pf[4 * ks + 0], srcA, 64);
            const float a1lo = __shfl(pf[4 * ks + 1], srcA, 64);
            const float a0hi = __shfl(pf[4 * ks + 2], srcA, 64);
            const float a1hi = __shfl(pf[4 * ks + 3], srcA, 64);
            const float b0lo = __shfl(pf[4 * ks + 0], srcB, 64);
            const float b1lo = __shfl(pf[4 * ks + 1], srcB, 64);
            const float b0hi = __shfl(pf[4 * ks + 2], srcB, 64);
            const float b1hi = __shfl(pf[4 * ks + 3], srcB, 64);
            U8 af;
            af.u[0] = __float_as_uint(hi ? a0hi : a0lo);
            af.u[1] = __float_as_uint(hi ? a1hi : a1lo);
            af.u[2] = __float_as_uint(hi ? b0hi : b0lo);
            af.u[3] = __float_as_uint(hi ? b1hi : b1lo);
#pragma unroll
            for (int dt = 0; dt < 4; ++dt) {
                const int D = rh + 16 * dt;
                const int c = 16 * W + 8 * T + 4 * ks + g;
                const short8 bf = *(const short8*)(smem + kOffCbt + D * 1024 +
                                                   ((c ^ (D & 7)) << 4));
                acc2[dt] = __builtin_amdgcn_mfma_f32_16x16x32_bf16(
                    af.s, bf, acc2[dt], 0, 0, 0);
            }
        }
    }

    // ---- merge softmax-1 stats (4-way, barrier A)
    float Sr = (S4[0] + S4[1]) + (S4[2] + S4[3]);
    float Wr = (W4[0] + W4[1]) + (W4[2] + W4[3]);
    Sr += __shfl_xor(Sr, 16, 64);
    Sr += __shfl_xor(Sr, 32, 64);
    Wr += __shfl_xor(Wr, 16, 64);
    Wr += __shfl_xor(Wr, 32, 64);
    if (g == 0) { cS[tp][W][rh] = Sr; cW[tp][W][rh] = Wr; }
    __syncthreads();
    const float St = (cS[tp][0][rh] + cS[tp][1][rh]) +
                     (cS[tp][2][rh] + cS[tp][3][rh]);
    const float Wt = (cW[tp][0][rh] + cW[tp][1][rh]) +
                     (cW[tp][2][rh] + cW[tp][3][rh]);
    const float inv = 1.0f / St;
    const float kldd = kLn2 * (Wt * inv - __builtin_amdgcn_logf(St));

    // ============== loop B: avg_probs butterfly -> LDS atomics ============
#pragma unroll
    for (int T = 0; T < 2; ++T) {
        float ev[16];
#pragma unroll
        for (int k2 = 0; k2 < 8; ++k2) {
            const uint32_t pe = epk[8 * T + k2];
            ev[2 * k2] = __uint_as_float(pe << 16);
            ev[2 * k2 + 1] = __uint_as_float(pe & 0xffff0000u);
        }
#pragma unroll
        for (int j = 0; j < 16; ++j) ev[j] *= inv;
#pragma unroll
        for (int m = 1, nv = 8; m <= 8; m <<= 1, nv >>= 1) {
            const bool up_ = (rh & m) != 0;
#pragma unroll
            for (int t = 0; t < nv; ++t) {
                const float a = ev[t], b = ev[t + nv];
                const float keep = up_ ? b : a;
                const float send = up_ ? a : b;
                ev[t] = keep + __shfl_xor(send, m, 64);
            }
        }
        const int jr = ((rh & 1) << 3) | ((rh & 2) << 1) | ((rh & 4) >> 1) |
                       ((rh & 8) >> 3);
        atomicAdd(&avg1[128 * W + 64 * T + 16 * (jr >> 2) + 4 * g + (jr & 3)],
                  ev[0]);
    }

    // ---- S2 merge store + acc2 partial scatter (LDS f32 atomics)
    float S2r = (S24[0] + S24[1]) + (S24[2] + S24[3]);
    S2r += __shfl_xor(S2r, 16, 64);
    S2r += __shfl_xor(S2r, 32, 64);
    if (g == 0) cS2[tp][W][rh] = S2r;
#pragma unroll
    for (int dt = 0; dt < 4; ++dt) {
        if (dt == W) continue;  // wave-uniform branch
        float* dst = accZ + ((tp * 4 + dt) * 64 + l) * 4;
        atomicAdd(dst + 0, acc2[dt][0]);
        atomicAdd(dst + 1, acc2[dt][1]);
        atomicAdd(dst + 2, acc2[dt][2]);
        atomicAdd(dst + 3, acc2[dt][3]);
    }
    __syncthreads();  // barrier B: cS2 + accZ + avg atomics complete

    const float inv2 = 1.0f / ((cS2[tp][0][rh] + cS2[tp][1][rh]) +
                               (cS2[tp][2][rh] + cS2[tp][3][rh]));
    float ivi[4];
#pragma unroll
    for (int i = 0; i < 4; ++i) ivi[i] = __shfl(inv2, 4 * g + i, 64);

    // wave W owns dt = W (static select; rule #20)
    const f32x4 own = (W == 0) ? acc2[0] : (W == 1) ? acc2[1]
                     : (W == 2) ? acc2[2] : acc2[3];
    const float4 az = *(const float4*)(accZ + ((tp * 4 + W) * 64 + l) * 4);

    float kldc = 0.f;
#pragma unroll
    for (int i = 0; i < 4; ++i) {
        const float pq = (i == 0) ? (own[0] + az.x) : (i == 1) ? (own[1] + az.y)
                        : (i == 2) ? (own[2] + az.z) : (own[3] + az.w);
        const float qv = pq * ivi[i];
        const size_t oi = (size_t)(r0 + 4 * g + i) * 64 + rh + 16 * W;
        out[oi] = qv;
        const float zv = z[oi];
        kldc = fmaf(zv, zv - qv, kldc);
    }

    // ---- scalar + avg reductions (wave reductions before lane divergence)
    const float kc = wsum64(kldc) * kq;
    const float kd = wsum64(kldd) * 0.25f;  // 4 g-lanes duplicate each row
    const int slot = blockIdx.x & (kSlots - 1);
    float* gp = g_part + (size_t)slot * kStride;
    if (l == 0) {
        atomicAdd(&gp[513], kc);
        if (W == 0) atomicAdd(&gp[512], kd);
    }
    // avg1 complete since barrier B
    if (tid < 512) atomicAdd(&gp[tid], avg1[tid]);
}

__global__ __launch_bounds__(512) void k_final(const float* __restrict__ g_part,
                                               float* __restrict__ out) {
    __shared__ float red[8];
    const int tid = threadIdx.x;
    float sacc = 0.f;
#pragma unroll 8
    for (int i = 0; i < kSlots; ++i) sacc += g_part[(size_t)i * kStride + tid];
    const float avg = sacc * (1.0f / 65536.0f);
    const float t = avg * __logf(avg + kEpsP);
    const float sw = wsum64(t);
    if ((tid & 63) == 0) red[tid >> 6] = sw;
    __syncthreads();
    if (tid == 0) {
        float tot = 0.f;
#pragma unroll
        for (int i = 0; i < 8; ++i) tot += red[i];
        float sc0 = 0.f, sc1 = 0.f;
        for (int i = 0; i < kSlots; ++i) {
            sc0 += g_part[(size_t)i * kStride + 512];
            sc1 += g_part[(size_t)i * kStride + 513];
        }
        out[4194304] = (sc0 + sc1) * 0.125f;
        out[4194305] = __expf(-tot);
    }
}

extern "C" void kernel_launch(void* const* d_in, const int* in_sizes, int n_in,
                              void* d_out, int out_size, void* d_ws, size_t ws_size,
                              hipStream_t stream) {
    (void)in_sizes; (void)n_in; (void)out_size; (void)ws_size;
    const float* z   = (const float*)d_in[0];
    const float* kq  = (const float*)d_in[1];
    const float* cb  = (const float*)d_in[2];
    const float* gum = (const float*)d_in[3];
    float* out = (float*)d_out;

    uint16_t* cbN  = (uint16_t*)d_ws;
    uint16_t* cbNT = cbN + 32768;
    float* g_part  = (float*)(cbNT + 32768);

    (void)hipFuncSetAttribute((const void*)k_main,
                              hipFuncAttributeMaxDynamicSharedMemorySize,
                              kLdsBytes);
    (void)hipMemsetAsync(g_part, 0, kSlots * kStride * sizeof(float), stream);
    k_prep<<<128, 256, 0, stream>>>(cb, cbN, cbNT);
    k_main<<<1024, 1024, kLdsBytes, stream>>>(z, kq, gum, cbN, cbNT, out, g_part);
    k_final<<<1, 512, 0, stream>>>(g_part, out);
}

// Round 22
// 86.860 us; speedup vs baseline: 1.9910x; 1.9910x over previous
//
#include <hip/hip_runtime.h>
#include <cstdint>
#include <cstddef>

// VmfVectorQuantizer round 22: R20 champion + COALESCED gumbel stream.
// u is loaded linearly (full 128B lines, 1KB/wave-instruction), transposed
// through a wave-private 2KB LDS slab (XOR-swizzled, no barriers), and read
// back in the MFMA compute layout. Slab unions with epilogue avg4/accx.

typedef __attribute__((ext_vector_type(8))) short short8;
typedef __attribute__((ext_vector_type(4))) float f32x4;

namespace {
constexpr float kEpsG = 1e-10f;
constexpr float kEpsN = 1e-12f;
constexpr float kEpsP = 1e-7f;
constexpr float kLog2e = 1.4426950408889634f;
constexpr float kLn2 = 0.6931471805599453f;
constexpr int kSlots = 128;
constexpr int kStride = 520;
// dynamic LDS layout (bytes)
constexpr int kOffCbt = 65536;    // [64][512] bf16 swizzled      65536
constexpr int kOffCS  = 131072;   // cS/cW/cS2 [4][2][16] f32      1536
constexpr int kOffU   = 132608;   // union: ustage [8][2048]      16384
                                  //   epilogue: avg4 8192 + accx 16384
constexpr int kLdsBytes = 157184;
}

__device__ __forceinline__ float wsum64(float v) {
#pragma unroll
    for (int m = 1; m < 64; m <<= 1) v += __shfl_xor(v, m, 64);
    return v;
}
__device__ __forceinline__ uint32_t pk_bf16(float a, float b) {
    uint32_t ua = __float_as_uint(a), ub = __float_as_uint(b);
    ua += 0x7fffu + ((ua >> 16) & 1u);
    ub += 0x7fffu + ((ub >> 16) & 1u);
    return (ua >> 16) | (ub & 0xffff0000u);
}
__device__ __forceinline__ uint16_t bf16_rne(float a) {
    uint32_t ua = __float_as_uint(a);
    ua += 0x7fffu + ((ua >> 16) & 1u);
    return (uint16_t)(ua >> 16);
}
__device__ __forceinline__ float dot4(float4 v) {
    return v.x * v.x + v.y * v.y + v.z * v.z + v.w * v.w;
}

__global__ __launch_bounds__(256) void k_prep(const float* __restrict__ cb,
                                              uint16_t* __restrict__ cbN,
                                              uint16_t* __restrict__ cbNT) {
    const int row = blockIdx.x * 4 + (threadIdx.x >> 6);
    const int lane = threadIdx.x & 63;
    const float v = cb[row * 64 + lane];
    const float ss = wsum64(v * v);
    const float nv = v / fmaxf(sqrtf(ss), kEpsN);
    const uint16_t h = bf16_rne(nv);
    cbN[row * 64 + lane] = h;
    cbNT[lane * 512 + row] = h;
}

// ---- k_main: 1024 blocks x 512 threads (8 waves = 4 tile-pairs).
__global__ __launch_bounds__(512) void k_main(
    const float* __restrict__ z, const float* __restrict__ kqp,
    const float* __restrict__ gum, const uint16_t* __restrict__ cbN,
    const uint16_t* __restrict__ cbNT, float* __restrict__ out,
    float* __restrict__ g_part) {
    extern __shared__ float4 smem_al[];
    char* smem = (char*)smem_al;
    float (*cS)[2][16]  = (float(*)[2][16])(smem + kOffCS);
    float (*cW)[2][16]  = (float(*)[2][16])(smem + kOffCS + 512);
    float (*cS2)[2][16] = (float(*)[2][16])(smem + kOffCS + 1024);
    float* avg4 = (float*)(smem + kOffU);                      // epilogue
    float4 (*accx)[2][2][64] = (float4(*)[2][2][64])(smem + kOffU + 8192);

    const int tid = threadIdx.x;
    const int wv = tid >> 6;   // 0..7
    const int tp = wv >> 1;    // tile-pair 0..3
    const int W = wv & 1;      // code-half
    const int l = tid & 63;
    const int g = l >> 4;
    const int rh = l & 15;
    const int r0 = blockIdx.x * 64 + tp * 16;
    const int row = r0 + rh;
    const float kq = *kqp;

    float4* us16 = (float4*)(smem + kOffU + wv * 2048);  // wave-private slab

    // ---- stage codebook into swizzled LDS (coalesced 16B chunks) ----
#pragma unroll
    for (int it = 0; it < 16; ++it) {
        const int i = tid + 512 * it;          // 8192 chunks
        const uint4 v = ((const uint4*)cbN)[i];
        const int r = i >> 3, c = i & 7;
        *(uint4*)(smem + r * 128 + (((c ^ (r & 7))) << 4)) = v;
    }
#pragma unroll
    for (int it = 0; it < 8; ++it) {
        const int i = tid + 512 * it;          // 4096 chunks
        const uint4 v = ((const uint4*)cbNT)[i];
        const int d = i >> 6, c = i & 63;
        *(uint4*)(smem + kOffCbt + d * 1024 + ((c ^ (d & 7)) << 4)) = v;
    }

    // ---- z load + L2 normalize; fold kq*log2e into bf16 B-fragments
    const float* zr = z + (size_t)row * 64;
    const float4 a0 = *(const float4*)(zr + 8 * g);
    const float4 a1 = *(const float4*)(zr + 8 * g + 4);
    const float4 a2 = *(const float4*)(zr + 32 + 8 * g);
    const float4 a3 = *(const float4*)(zr + 36 + 8 * g);
    float ss = dot4(a0) + dot4(a1) + dot4(a2) + dot4(a3);
    ss += __shfl_xor(ss, 16, 64);
    ss += __shfl_xor(ss, 32, 64);
    const float scz = kq * kLog2e / fmaxf(sqrtf(ss), kEpsN);
    union U8 { short8 s; uint32_t u[4]; };
    U8 zb0, zb1;
    zb0.u[0] = pk_bf16(a0.x * scz, a0.y * scz);
    zb0.u[1] = pk_bf16(a0.z * scz, a0.w * scz);
    zb0.u[2] = pk_bf16(a1.x * scz, a1.y * scz);
    zb0.u[3] = pk_bf16(a1.z * scz, a1.w * scz);
    zb1.u[0] = pk_bf16(a2.x * scz, a2.y * scz);
    zb1.u[1] = pk_bf16(a2.z * scz, a2.w * scz);
    zb1.u[2] = pk_bf16(a3.x * scz, a3.y * scz);
    zb1.u[3] = pk_bf16(a3.z * scz, a3.w * scz);

    const float B1 = kq * kLog2e;  // static bound: x <= B1

    // ---- coalesced u staging helpers ----
    // LOADU: instr covers 8 rows x 128B contiguous; lane reads 16B.
    const int srow0 = l >> 3;        // 0..7
    const int scol = l & 7;          // 16B chunk in 128B row segment
    const float* gbase = gum + (size_t)r0 * 512 + 256 * W + scol * 4;
#define LOADU(S0, S1, T, H)                                                  \
    {                                                                        \
        const float* p = gbase + 64 * (T) + 32 * (H);                        \
        S0 = *(const float4*)(p + (size_t)(srow0)*512);                      \
        S1 = *(const float4*)(p + (size_t)(srow0 + 8) * 512);                \
    }
    // WRITEU: slab chunk = row*8 + (col ^ (row&7))
#define WRITEU(S0, S1)                                                       \
    {                                                                        \
        us16[srow0 * 8 + (scol ^ (srow0 & 7))] = S0;                         \
        us16[(srow0 + 8) * 8 + (scol ^ ((srow0 + 8) & 7))] = S1;             \
    }

    float4 s0, s1;
    LOADU(s0, s1, 0, 0)  // tile 0, half 0

    __syncthreads();  // LDS codebook ready

    // ============== fused loop: GEMM1 -> e -> gumbel -> GEMM2 =============
    uint32_t epk[32];
    float S4[4] = {0.f, 0.f, 0.f, 0.f}, W4[4] = {0.f, 0.f, 0.f, 0.f};
    float S24[4] = {0.f, 0.f, 0.f, 0.f};
    f32x4 acc2[4];
#pragma unroll
    for (int dt = 0; dt < 4; ++dt) acc2[dt] = (f32x4){0.f, 0.f, 0.f, 0.f};
    const int srcA = rh + 16 * ((2 * g) & 3);
    const int srcB = rh + 16 * ((2 * g + 1) & 3);
    const bool hi = (g & 2) != 0;

#define QUARTET(T, Q, PF)                                                    \
    {                                                                        \
        const int R = 256 * W + 64 * (T) + 16 * (Q) + rh;                    \
        const char* rb = smem + R * 128;                                     \
        const short8 ca0 = *(const short8*)(rb + ((g ^ (R & 7)) << 4));      \
        const short8 ca1 = *(const short8*)(rb + (((g + 4) ^ (R & 7)) << 4));\
        f32x4 acc = {0.f, 0.f, 0.f, 0.f};                                    \
        acc = __builtin_amdgcn_mfma_f32_16x16x32_bf16(ca0, zb0.s, acc, 0, 0, 0); \
        acc = __builtin_amdgcn_mfma_f32_16x16x32_bf16(ca1, zb1.s, acc, 0, 0, 0); \
        const float4 uq = us16[rh * 8 + (((((Q)&1) * 4) + g) ^ (rh & 7))];   \
        const float uu[4] = {uq.x, uq.y, uq.z, uq.w};                        \
        float e4[4], e2v[4];                                                 \
        _Pragma("unroll") for (int i = 0; i < 4; ++i) {                      \
            const float d = acc[i] - B1;                                     \
            const float e = __builtin_amdgcn_exp2f(d);                       \
            e4[i] = e;                                                       \
            S4[i] += e;                                                      \
            W4[i] = fmaf(d, e, W4[i]);                                       \
            const float lg = __builtin_amdgcn_logf(uu[i] + kEpsG);           \
            const float inr = fmaf(lg, -kLn2, kEpsG);                        \
            const float r = __builtin_amdgcn_rcpf(inr);                      \
            const float t = e * r;                                           \
            const float e2 = t * t;                                          \
            e2v[i] = e2;                                                     \
            S24[i] += e2;                                                    \
        }                                                                    \
        epk[8 * (T) + 2 * (Q)] = pk_bf16(e4[0], e4[1]);                      \
        epk[8 * (T) + 2 * (Q) + 1] = pk_bf16(e4[2], e4[3]);                  \
        PF[2 * (Q)&3 ? 0 : 0] = PF[0];  /* no-op to keep macro simple */     \
        PF[((Q)&1) * 2 + 0 + (((Q) >> 31) & 0)] = PF[((Q)&1) * 2];           \
    }
#undef QUARTET
    // (macro above unused; explicit quartet fn below)

#define QRT(T, Q, P0, P1)                                                    \
    {                                                                        \
        const int R = 256 * W + 64 * (T) + 16 * (Q) + rh;                    \
        const char* rb = smem + R * 128;                                     \
        const short8 ca0 = *(const short8*)(rb + ((g ^ (R & 7)) << 4));      \
        const short8 ca1 = *(const short8*)(rb + (((g + 4) ^ (R & 7)) << 4));\
        f32x4 acc = {0.f, 0.f, 0.f, 0.f};                                    \
        acc = __builtin_amdgcn_mfma_f32_16x16x32_bf16(ca0, zb0.s, acc, 0, 0, 0); \
        acc = __builtin_amdgcn_mfma_f32_16x16x32_bf16(ca1, zb1.s, acc, 0, 0, 0); \
        const float4 uq = us16[rh * 8 + ((((Q & 1) * 4) + g) ^ (rh & 7))];   \
        const float uu[4] = {uq.x, uq.y, uq.z, uq.w};                        \
        float e4[4], e2v[4];                                                 \
        _Pragma("unroll") for (int i = 0; i < 4; ++i) {                      \
            const float d = acc[i] - B1;                                     \
            const float e = __builtin_amdgcn_exp2f(d);                       \
            e4[i] = e;                                                       \
            S4[i] += e;                                                      \
            W4[i] = fmaf(d, e, W4[i]);                                       \
            const float lg = __builtin_amdgcn_logf(uu[i] + kEpsG);           \
            const float inr = fmaf(lg, -kLn2, kEpsG);                        \
            const float r = __builtin_amdgcn_rcpf(inr);                      \
            const float t = e * r;                                           \
            const float e2 = t * t;                                          \
            e2v[i] = e2;                                                     \
            S24[i] += e2;                                                    \
        }                                                                    \
        epk[8 * (T) + 2 * (Q)] = pk_bf16(e4[0], e4[1]);                      \
        epk[8 * (T) + 2 * (Q) + 1] = pk_bf16(e4[2], e4[3]);                  \
        P0 = __uint_as_float(pk_bf16(e2v[0], e2v[1]));                       \
        P1 = __uint_as_float(pk_bf16(e2v[2], e2v[3]));                       \
    }

#define EXCH(T, KS, PFA, PFB, PFC, PFD)                                      \
    {                                                                        \
        const float a0lo = __shfl(PFA, srcA, 64);                            \
        const float a1lo = __shfl(PFB, srcA, 64);                            \
        const float a0hi = __shfl(PFC, srcA, 64);                            \
        const float a1hi = __shfl(PFD, srcA, 64);                            \
        const float b0lo = __shfl(PFA, srcB, 64);                            \
        const float b1lo = __shfl(PFB, srcB, 64);                            \
        const float b0hi = __shfl(PFC, srcB, 64);                            \
        const float b1hi = __shfl(PFD, srcB, 64);                            \
        U8 af;                                                               \
        af.u[0] = __float_as_uint(hi ? a0hi : a0lo);                         \
        af.u[1] = __float_as_uint(hi ? a1hi : a1lo);                         \
        af.u[2] = __float_as_uint(hi ? b0hi : b0lo);                         \
        af.u[3] = __float_as_uint(hi ? b1hi : b1lo);                         \
        _Pragma("unroll") for (int dt = 0; dt < 4; ++dt) {                   \
            const int D = rh + 16 * dt;                                      \
            const int c = 32 * W + 8 * (T) + 4 * (KS) + g;                   \
            const short8 bf = *(const short8*)(smem + kOffCbt + D * 1024 +   \
                                               ((c ^ (D & 7)) << 4));        \
            acc2[dt] = __builtin_amdgcn_mfma_f32_16x16x32_bf16(              \
                af.s, bf, acc2[dt], 0, 0, 0);                                \
        }                                                                    \
    }

#define FTILE(T, LAST)                                                       \
    {                                                                        \
        float p0, p1, p2, p3;                                                \
        WRITEU(s0, s1)                   /* half0 -> slab */                 \
        LOADU(s0, s1, T, 1)              /* issue half1 */                   \
        QRT(T, 0, p0, p1)                                                    \
        QRT(T, 1, p2, p3)                                                    \
        EXCH(T, 0, p0, p1, p2, p3)                                           \
        WRITEU(s0, s1)                   /* half1 -> slab (vmcnt wait) */    \
        if (!(LAST)) LOADU(s0, s1, (T) + 1, 0) /* issue next tile half0 */   \
        QRT(T, 2, p0, p1)                                                    \
        QRT(T, 3, p2, p3)                                                    \
        EXCH(T, 1, p0, p1, p2, p3)                                           \
    }

    FTILE(0, 0)
    FTILE(1, 0)
    FTILE(2, 0)
    FTILE(3, 1)

    // ---- merge softmax-1 stats (single barrier)
    float Sr = (S4[0] + S4[1]) + (S4[2] + S4[3]);
    float Wr = (W4[0] + W4[1]) + (W4[2] + W4[3]);
    Sr += __shfl_xor(Sr, 16, 64);
    Sr += __shfl_xor(Sr, 32, 64);
    Wr += __shfl_xor(Wr, 16, 64);
    Wr += __shfl_xor(Wr, 32, 64);
    if (g == 0) { cS[tp][W][rh] = Sr; cW[tp][W][rh] = Wr; }
    __syncthreads();  // barrier A: all slab reads done; epilogue may reuse
    const float St = cS[tp][0][rh] + cS[tp][1][rh];
    const float Wt = cW[tp][0][rh] + cW[tp][1][rh];
    const float inv = 1.0f / St;
    const float kldd = kLn2 * (Wt * inv - __builtin_amdgcn_logf(St));

    // ============== loop B: avg_probs butterfly ===========================
#pragma unroll
    for (int T = 0; T < 4; ++T) {
        float ev[16];
#pragma unroll
        for (int k2 = 0; k2 < 8; ++k2) {
            const uint32_t pe = epk[8 * T + k2];
            ev[2 * k2] = __uint_as_float(pe << 16);
            ev[2 * k2 + 1] = __uint_as_float(pe & 0xffff0000u);
        }
#pragma unroll
        for (int j = 0; j < 16; ++j) ev[j] *= inv;
#pragma unroll
        for (int m = 1, nv = 8; m <= 8; m <<= 1, nv >>= 1) {
            const bool up_ = (rh & m) != 0;
#pragma unroll
            for (int t = 0; t < nv; ++t) {
                const float a = ev[t], b = ev[t + nv];
                const float keep = up_ ? b : a;
                const float send = up_ ? a : b;
                ev[t] = keep + __shfl_xor(send, m, 64);
            }
        }
        const int jr = ((rh & 1) << 3) | ((rh & 2) << 1) | ((rh & 4) >> 1) |
                       ((rh & 8) >> 3);
        avg4[tp * 512 + 256 * W + 64 * T + 16 * (jr >> 2) + 4 * g + (jr & 3)] =
            ev[0];
    }

    // ---- merge S2 + exchange acc2 partials (single barrier)
    float S2r = (S24[0] + S24[1]) + (S24[2] + S24[3]);
    S2r += __shfl_xor(S2r, 16, 64);
    S2r += __shfl_xor(S2r, 32, 64);
    if (g == 0) cS2[tp][W][rh] = S2r;
    if (W == 0) {
        accx[tp][0][0][l] = make_float4(acc2[2][0], acc2[2][1], acc2[2][2], acc2[2][3]);
        accx[tp][0][1][l] = make_float4(acc2[3][0], acc2[3][1], acc2[3][2], acc2[3][3]);
    } else {
        accx[tp][1][0][l] = make_float4(acc2[0][0], acc2[0][1], acc2[0][2], acc2[0][3]);
        accx[tp][1][1][l] = make_float4(acc2[1][0], acc2[1][1], acc2[1][2], acc2[1][3]);
    }
    __syncthreads();
    const float inv2 = 1.0f / (cS2[tp][0][rh] + cS2[tp][1][rh]);
    float ivi[4];
#pragma unroll
    for (int i = 0; i < 4; ++i) ivi[i] = __shfl(inv2, 4 * g + i, 64);

    float kldc = 0.f;
#define EPI(OV, XV, DT)                                                       \
    {                                                                         \
        const float oq[4] = {OV[0] + XV.x, OV[1] + XV.y, OV[2] + XV.z,        \
                             OV[3] + XV.w};                                   \
        _Pragma("unroll") for (int i = 0; i < 4; ++i) {                       \
            const float q = oq[i] * ivi[i];                                   \
            const size_t oi = (size_t)(r0 + 4 * g + i) * 64 + rh + 16 * (DT); \
            out[oi] = q;                                                      \
            const float zv = z[oi];                                           \
            kldc = fmaf(zv, zv - q, kldc);                                    \
        }                                                                     \
    }
    if (W == 0) {
        const float4 x0 = accx[tp][1][0][l];
        const float4 x1 = accx[tp][1][1][l];
        EPI(acc2[0], x0, 0)
        EPI(acc2[1], x1, 1)
    } else {
        const float4 x0 = accx[tp][0][0][l];
        const float4 x1 = accx[tp][0][1][l];
        EPI(acc2[2], x0, 2)
        EPI(acc2[3], x1, 3)
    }

    // ---- scalar + avg reductions (wave reductions before divergence)
    const int slot = blockIdx.x & (kSlots - 1);
    float* gp = g_part + (size_t)slot * kStride;
    const float kc = wsum64(kldc) * kq;
    const float kd = wsum64(kldd) * 0.25f;
    if (l == 0) {
        atomicAdd(&gp[513], kc);
        if (W == 0) atomicAdd(&gp[512], kd);
    }
    // avg4 fully written before the accx barrier; flush 4 codes/thread
    const float av = avg4[tid] + avg4[512 + tid] + avg4[1024 + tid] +
                     avg4[1536 + tid];
    atomicAdd(&gp[tid], av);
}

__global__ __launch_bounds__(512) void k_final(const float* __restrict__ g_part,
                                               float* __restrict__ out) {
    __shared__ float red[8];
    const int tid = threadIdx.x;
    float sacc = 0.f;
#pragma unroll 8
    for (int i = 0; i < kSlots; ++i) sacc += g_part[(size_t)i * kStride + tid];
    const float avg = sacc * (1.0f / 65536.0f);
    const float t = avg * __logf(avg + kEpsP);
    const float sw = wsum64(t);
    if ((tid & 63) == 0) red[tid >> 6] = sw;
    __syncthreads();
    if (tid == 0) {
        float tot = 0.f;
#pragma unroll
        for (int i = 0; i < 8; ++i) tot += red[i];
        float sc0 = 0.f, sc1 = 0.f;
        for (int i = 0; i < kSlots; ++i) {
            sc0 += g_part[(size_t)i * kStride + 512];
            sc1 += g_part[(size_t)i * kStride + 513];
        }
        out[4194304] = (sc0 + sc1) * 0.125f;
        out[4194305] = __expf(-tot);
    }
}

extern "C" void kernel_launch(void* const* d_in, const int* in_sizes, int n_in,
                              void* d_out, int out_size, void* d_ws, size_t ws_size,
                              hipStream_t stream) {
    (void)in_sizes; (void)n_in; (void)out_size; (void)ws_size;
    const float* z   = (const float*)d_in[0];
    const float* kq  = (const float*)d_in[1];
    const float* cb  = (const float*)d_in[2];
    const float* gum = (const float*)d_in[3];
    float* out = (float*)d_out;

    uint16_t* cbN  = (uint16_t*)d_ws;
    uint16_t* cbNT = cbN + 32768;
    float* g_part  = (float*)(cbNT + 32768);

    (void)hipFuncSetAttribute((const void*)k_main,
                              hipFuncAttributeMaxDynamicSharedMemorySize,
                              kLdsBytes);
    (void)hipMemsetAsync(g_part, 0, kSlots * kStride * sizeof(float), stream);
    k_prep<<<128, 256, 0, stream>>>(cb, cbN, cbNT);
    k_main<<<1024, 512, kLdsBytes, stream>>>(z, kq, gum, cbN, cbNT, out, g_part);
    k_final<<<1, 512, 0, stream>>>(g_part, out);
}